// Round 3
// baseline (116.637 us; speedup 1.0000x reference)
//
#include <hip/hip_runtime.h>
#include <math.h>

#define BB    8
#define TDIM  64
#define NN    128
#define DD    128
#define TTOUT 62      // T-2
#define W3    384     // 3*N
#define LG    136     // ushort stride, 128-wide bf16 tiles (272B rows)
#define LPF   44      // ushort stride, sFt 32-wide tiles (88B rows, 8B-aligned odd cols)
#define LPP   44      // ushort stride, sP
#define LW    72      // ushort stride, FFN weight tiles (144B rows)

typedef __attribute__((ext_vector_type(8))) short bf16x8;
typedef __attribute__((ext_vector_type(4))) float f32x4;

__device__ __forceinline__ float sigf(float x){ return 1.0f/(1.0f+__expf(-x)); }
__device__ __forceinline__ unsigned short f2bf(float x){
  union{float f; unsigned u;} v; v.f=x;
  unsigned r = v.u + 0x7FFFu + ((v.u>>16)&1u);   // RNE
  return (unsigned short)(r>>16);
}

// K_pre: per t-block: rscale, gbf = bf16(rscale*sig*feat), fbf = bf16(feat), ssum = colsum(G) fp32
template<bool FBF>
__global__ __launch_bounds__(512) void k_pre(const float* __restrict__ feat,
    const float* __restrict__ w, unsigned short* __restrict__ gbf,
    unsigned short* __restrict__ fbf, float* __restrict__ rscale,
    float* __restrict__ ssum){
  __shared__ float sSig[DD];
  __shared__ float sPart[8*DD];
  const int bt = blockIdx.x, tid = threadIdx.x;
  if(tid < DD) sSig[tid] = sigf(w[tid]);
  __syncthreads();
  const int row = tid >> 2, q = tid & 3;
  const float* fp = feat + ((size_t)bt*NN + row)*DD + q*32;
  float f[32], g[32];
  #pragma unroll
  for(int i=0;i<8;i++){
    float4 v = *(const float4*)(fp + i*4);
    f[i*4]=v.x; f[i*4+1]=v.y; f[i*4+2]=v.z; f[i*4+3]=v.w;
  }
  float ss = 0.f;
  #pragma unroll
  for(int j=0;j<32;j++){ g[j] = f[j]*sSig[q*32+j]; ss += g[j]*g[j]; }
  ss += __shfl_xor(ss,1); ss += __shfl_xor(ss,2);
  float rs = 1.0f / fmaxf(sqrtf(ss), 1e-12f);
  if(q==0) rscale[(size_t)bt*NN + row] = rs;
  #pragma unroll
  for(int j=0;j<32;j++) g[j] *= rs;
  {
    unsigned u[16];
    #pragma unroll
    for(int j=0;j<16;j++) u[j] = (unsigned)f2bf(g[2*j]) | ((unsigned)f2bf(g[2*j+1])<<16);
    uint4* dst = (uint4*)(gbf + ((size_t)bt*NN+row)*DD + q*32);
    #pragma unroll
    for(int i=0;i<4;i++) dst[i] = *(uint4*)&u[i*4];
  }
  if(FBF){
    unsigned u[16];
    #pragma unroll
    for(int j=0;j<16;j++) u[j] = (unsigned)f2bf(f[2*j]) | ((unsigned)f2bf(f[2*j+1])<<16);
    uint4* dst = (uint4*)(fbf + ((size_t)bt*NN+row)*DD + q*32);
    #pragma unroll
    for(int i=0;i<4;i++) dst[i] = *(uint4*)&u[i*4];
  }
  // column sums of G over this block's 128 rows (fp32, pre-rounding)
  #pragma unroll
  for(int k=4;k<64;k<<=1){
    #pragma unroll
    for(int j=0;j<32;j++) g[j] += __shfl_xor(g[j], k);
  }
  const int lane = tid & 63, wid = tid >> 6;
  if((lane>>2)==0){
    #pragma unroll
    for(int j=0;j<32;j++) sPart[wid*DD + q*32 + j] = g[j];
  }
  __syncthreads();
  if(tid < DD){
    float s = 0.f;
    #pragma unroll
    for(int wv=0; wv<8; wv++) s += sPart[wv*DD + tid];
    ssum[(size_t)bt*DD + tid] = s;
  }
}

// K_wt: W1,W2 -> transposed bf16
__global__ void k_wt(const float* __restrict__ W1, const float* __restrict__ W2,
                     unsigned short* __restrict__ W1T, unsigned short* __restrict__ W2T){
  int k = blockIdx.x & 127, m = blockIdx.x >> 7;
  int n = threadIdx.x;
  const float* W = m ? W2 : W1;
  unsigned short* WT = m ? W2T : W1T;
  WT[n*DD + k] = f2bf(W[(size_t)k*DD + n]);
}

// K_d5: d5[r][k] = rscale_r * sum_d feat[r][d]*sig[d]*ssum[t(r)-2+k][d], k=0..4 (fp32, sign-accurate)
__global__ __launch_bounds__(256) void k_d5(const float* __restrict__ feat,
    const float* __restrict__ w, const float* __restrict__ rscale,
    const float* __restrict__ ssum, float* __restrict__ d5){
  __shared__ float s5[5*DD];
  const int tb = blockIdx.x, tid = threadIdx.x;
  for(int e=tid; e<5*DD; e+=256){
    int k = e>>7, d = e&127;
    int t2 = (tb & 63) - 2 + k;
    float v = 0.f;
    if(t2 >= 0 && t2 < TDIM) v = sigf(w[d]) * ssum[(size_t)(tb + k - 2)*DD + d];
    s5[k*DD + d] = v;
  }
  __syncthreads();
  const int row = tid>>1, h = tid&1;
  const float* fp = feat + ((size_t)tb*NN + row)*DD + h*64;
  float a0=0,a1=0,a2=0,a3=0,a4=0;
  #pragma unroll
  for(int i=0;i<16;i++){
    float4 v = *(const float4*)(fp + i*4);
    const float* s0 = s5 + h*64 + i*4;
    a0 += v.x*s0[0*DD+0] + v.y*s0[0*DD+1] + v.z*s0[0*DD+2] + v.w*s0[0*DD+3];
    a1 += v.x*s0[1*DD+0] + v.y*s0[1*DD+1] + v.z*s0[1*DD+2] + v.w*s0[1*DD+3];
    a2 += v.x*s0[2*DD+0] + v.y*s0[2*DD+1] + v.z*s0[2*DD+2] + v.w*s0[2*DD+3];
    a3 += v.x*s0[3*DD+0] + v.y*s0[3*DD+1] + v.z*s0[3*DD+2] + v.w*s0[3*DD+3];
    a4 += v.x*s0[4*DD+0] + v.y*s0[4*DD+1] + v.z*s0[4*DD+2] + v.w*s0[4*DD+3];
  }
  a0 += __shfl_xor(a0,1); a1 += __shfl_xor(a1,1); a2 += __shfl_xor(a2,1);
  a3 += __shfl_xor(a3,1); a4 += __shfl_xor(a4,1);
  if(h==0){
    float rs = rscale[(size_t)tb*NN + row];
    float* dp = d5 + ((size_t)tb*NN + row)*5;
    dp[0]=a0*rs; dp[1]=a1*rs; dp[2]=a2*rs; dp[3]=a3*rs; dp[4]=a4*rs;
  }
}

// K_main: per (b,tt): dis from d5; P = dis*(G·Gᵀ)*dis (MFMA); agg = P·F (MFMA); FFN (MFMA); res+LN
template<bool FBF>
__global__ __launch_bounds__(512,4) void k_main(
    const float* __restrict__ feat,
    const unsigned short* __restrict__ gbf,
    const unsigned short* __restrict__ fbf,
    const float* __restrict__ d5,
    const unsigned short* __restrict__ W1T, const float* __restrict__ b1,
    const unsigned short* __restrict__ W2T, const float* __restrict__ b2,
    const float* __restrict__ gamma, const float* __restrict__ beta,
    float* __restrict__ out)
{
  __shared__ __align__(16) unsigned short sm[33024];
  __shared__ float sDis[W3];
  unsigned short* sA  = sm;            // 128 x LG : G rows 256..383 (A of gram; later agg, h)
  unsigned short* sG  = sm + 17408;    // 32 x LG  : G chunk rows
  unsigned short* sFt = sm + 21760;    // 128 x LPF: F chunk transposed [d][n]
  unsigned short* sP  = sm + 27392;    // 128 x LPP: P chunk bf16
  unsigned short* sWt = sm + 17408;    // 128 x LW : FFN weight tiles (overlay)

  const int bt2 = blockIdx.x;
  const int tid = threadIdx.x;
  const int rowBase = (bt2/TTOUT)*TDIM*NN + (bt2%TTOUT)*NN;

  const int lane = tid & 63, wid = tid >> 6;
  const int l15 = lane & 15, l4 = lane >> 4;
  const int m0 = wid * 16;

  // dis for all 384 window rows
  if(tid < W3){
    int jb = tid >> 7;
    const float* dp = d5 + (size_t)(rowBase + tid)*5 + (2 - jb);
    float deg = dp[0] + dp[1] + dp[2];
    sDis[tid] = (deg > 0.f) ? rsqrtf(fmaxf(deg, 1e-38f)) : 0.f;
  }

  // sA copy: 128 rows x 16 segs
  #pragma unroll
  for(int it=0; it<4; ++it){
    int e = it*512 + tid;
    int r = e >> 4, sg = e & 15;
    uint4 v = *(const uint4*)(gbf + (size_t)(rowBase+256+r)*DD + sg*8);
    *(uint4*)(sA + r*LG + sg*8) = v;
  }

  f32x4 acc2[8];
  #pragma unroll
  for(int i=0;i<8;i++) acc2[i] = (f32x4){0.f,0.f,0.f,0.f};

  for(int c=0; c<12; ++c){
    const int n0 = c*32;
    __syncthreads();   // prev phase2 done with sG/sFt/sP (c=0: sA/sDis ready)
    // sG: 32 rows x 16 segs = 512
    {
      int r = tid >> 4, sg = tid & 15;
      uint4 v = *(const uint4*)(gbf + (size_t)(rowBase+n0+r)*DD + sg*8);
      *(uint4*)(sG + r*LG + sg*8) = v;
    }
    // sFt: transpose-stage F chunk; thread = (col-pair, row-group of 4)
    {
      int p = tid & 63, rg = tid >> 6;
      int d0 = p*2, r0 = rg*4;
      unsigned v0,v1,v2,v3;
      if(FBF){
        v0 = *(const unsigned*)(fbf + (size_t)(rowBase+n0+r0+0)*DD + d0);
        v1 = *(const unsigned*)(fbf + (size_t)(rowBase+n0+r0+1)*DD + d0);
        v2 = *(const unsigned*)(fbf + (size_t)(rowBase+n0+r0+2)*DD + d0);
        v3 = *(const unsigned*)(fbf + (size_t)(rowBase+n0+r0+3)*DD + d0);
      } else {
        float2 a0 = *(const float2*)(feat + (size_t)(rowBase+n0+r0+0)*DD + d0);
        float2 a1 = *(const float2*)(feat + (size_t)(rowBase+n0+r0+1)*DD + d0);
        float2 a2 = *(const float2*)(feat + (size_t)(rowBase+n0+r0+2)*DD + d0);
        float2 a3 = *(const float2*)(feat + (size_t)(rowBase+n0+r0+3)*DD + d0);
        v0 = (unsigned)f2bf(a0.x) | ((unsigned)f2bf(a0.y)<<16);
        v1 = (unsigned)f2bf(a1.x) | ((unsigned)f2bf(a1.y)<<16);
        v2 = (unsigned)f2bf(a2.x) | ((unsigned)f2bf(a2.y)<<16);
        v3 = (unsigned)f2bf(a3.x) | ((unsigned)f2bf(a3.y)<<16);
      }
      uint2 lo, hi;
      lo.x = (v0 & 0xffffu) | (v1 << 16);
      lo.y = (v2 & 0xffffu) | (v3 << 16);
      hi.x = (v0 >> 16) | (v1 & 0xffff0000u);
      hi.y = (v2 >> 16) | (v3 & 0xffff0000u);
      *(uint2*)(sFt + (size_t)d0*LPF + r0)     = lo;
      *(uint2*)(sFt + (size_t)(d0+1)*LPF + r0) = hi;
    }
    __syncthreads();

    // phase1: P[:, n0:+32] = A(128xK128) x Gchunk^T, dis applied in epilogue
    f32x4 p0 = {0.f,0.f,0.f,0.f}, p1 = {0.f,0.f,0.f,0.f};
    #pragma unroll
    for(int ks=0; ks<4; ++ks){
      bf16x8 aA  = *(const bf16x8*)&sA[(m0+l15)*LG + ks*32 + l4*8];
      bf16x8 bg0 = *(const bf16x8*)&sG[( 0+l15)*LG + ks*32 + l4*8];
      bf16x8 bg1 = *(const bf16x8*)&sG[(16+l15)*LG + ks*32 + l4*8];
      p0 = __builtin_amdgcn_mfma_f32_16x16x32_bf16(aA, bg0, p0, 0,0,0);
      p1 = __builtin_amdgcn_mfma_f32_16x16x32_bf16(aA, bg1, p1, 0,0,0);
    }
    {
      float dn0 = sDis[n0 + l15], dn1 = sDis[n0 + 16 + l15];
      #pragma unroll
      for(int r=0;r<4;r++){
        float dm = sDis[256 + m0 + l4*4 + r];
        sP[(m0+l4*4+r)*LPP +  0 + l15] = f2bf(p0[r]*dm*dn0);
        sP[(m0+l4*4+r)*LPP + 16 + l15] = f2bf(p1[r]*dm*dn1);
      }
    }
    __syncthreads();

    // phase2: agg += P(128x32) x F(32x128)
    bf16x8 aP = *(const bf16x8*)&sP[(m0+l15)*LPP + l4*8];
    #pragma unroll
    for(int dt=0; dt<8; ++dt){
      bf16x8 bF = *(const bf16x8*)&sFt[(dt*16+l15)*LPF + l4*8];
      acc2[dt] = __builtin_amdgcn_mfma_f32_16x16x32_bf16(aP, bF, acc2[dt], 0,0,0);
    }
  }

  // agg -> sA (bf16); wave-strip-local, no sync needed
  #pragma unroll
  for(int dt=0; dt<8; ++dt)
    #pragma unroll
    for(int r=0;r<4;r++)
      sA[(m0+l4*4+r)*LG + dt*16+l15] = f2bf(acc2[dt][r]);

  // GEMM1: h = relu(agg @ W1 + b1)
  f32x4 acch[8];
  #pragma unroll
  for(int dt=0; dt<8; ++dt){
    float bv = b1[dt*16+l15];
    acch[dt] = (f32x4){bv,bv,bv,bv};
  }
  for(int kh=0; kh<2; ++kh){
    __syncthreads();   // all phase2/前 sWt reads done
    #pragma unroll
    for(int it=0; it<2; ++it){
      int e = it*512 + tid;       // 1024: 128 rows x 8 segs
      int n = e>>3, sg = e&7;
      uint4 v = *(const uint4*)(W1T + (size_t)n*DD + kh*64 + sg*8);
      *(uint4*)(sWt + n*LW + sg*8) = v;
    }
    __syncthreads();
    #pragma unroll
    for(int ks=0; ks<2; ++ks){
      bf16x8 aA = *(const bf16x8*)&sA[(m0+l15)*LG + kh*64 + ks*32 + l4*8];
      #pragma unroll
      for(int dt=0; dt<8; ++dt){
        bf16x8 bW = *(const bf16x8*)&sWt[(dt*16+l15)*LW + ks*32 + l4*8];
        acch[dt] = __builtin_amdgcn_mfma_f32_16x16x32_bf16(aA, bW, acch[dt], 0,0,0);
      }
    }
  }
  __syncthreads();   // GEMM1 done before h overwrites sA (A-reads were strip-local, but keep safe)
  #pragma unroll
  for(int dt=0; dt<8; ++dt)
    #pragma unroll
    for(int r=0;r<4;r++)
      sA[(m0+l4*4+r)*LG + dt*16+l15] = f2bf(fmaxf(acch[dt][r], 0.f));

  // GEMM2: o = h @ W2 + b2
  f32x4 acco[8];
  #pragma unroll
  for(int dt=0; dt<8; ++dt){
    float bv = b2[dt*16+l15];
    acco[dt] = (f32x4){bv,bv,bv,bv};
  }
  for(int kh=0; kh<2; ++kh){
    __syncthreads();
    #pragma unroll
    for(int it=0; it<2; ++it){
      int e = it*512 + tid;
      int n = e>>3, sg = e&7;
      uint4 v = *(const uint4*)(W2T + (size_t)n*DD + kh*64 + sg*8);
      *(uint4*)(sWt + n*LW + sg*8) = v;
    }
    __syncthreads();
    #pragma unroll
    for(int ks=0; ks<2; ++ks){
      bf16x8 aA = *(const bf16x8*)&sA[(m0+l15)*LG + kh*64 + ks*32 + l4*8];
      #pragma unroll
      for(int dt=0; dt<8; ++dt){
        bf16x8 bW = *(const bf16x8*)&sWt[(dt*16+l15)*LW + ks*32 + l4*8];
        acco[dt] = __builtin_amdgcn_mfma_f32_16x16x32_bf16(aA, bW, acco[dt], 0,0,0);
      }
    }
  }

  // residual + LayerNorm (fp32)
  const float* fres = feat + (size_t)(rowBase + 256)*DD;
  #pragma unroll
  for(int r=0;r<4;r++){
    int m = m0 + l4*4 + r;
    float vals[8]; float s1 = 0.f, s2 = 0.f;
    #pragma unroll
    for(int dt=0; dt<8; ++dt){
      int d = dt*16 + l15;
      float v = acco[dt][r] + fres[(size_t)m*DD + d];
      vals[dt] = v; s1 += v; s2 += v*v;
    }
    #pragma unroll
    for(int k=1;k<16;k<<=1){ s1 += __shfl_xor(s1,k); s2 += __shfl_xor(s2,k); }
    float mu   = s1*(1.0f/DD);
    float rstd = rsqrtf(s2*(1.0f/DD) - mu*mu + 1e-5f);
    #pragma unroll
    for(int dt=0; dt<8; ++dt){
      int d = dt*16 + l15;
      out[((size_t)bt2*NN + m)*DD + d] = (vals[dt]-mu)*rstd*gamma[d] + beta[d];
    }
  }
}

extern "C" void kernel_launch(void* const* d_in, const int* in_sizes, int n_in,
                              void* d_out, int out_size, void* d_ws, size_t ws_size,
                              hipStream_t stream){
  const float* feat  = (const float*)d_in[0];
  const float* w     = (const float*)d_in[1];
  const float* W1    = (const float*)d_in[2];
  const float* b1    = (const float*)d_in[3];
  const float* W2    = (const float*)d_in[4];
  const float* b2    = (const float*)d_in[5];
  const float* gamma = (const float*)d_in[6];
  const float* beta  = (const float*)d_in[7];
  float* out = (float*)d_out;

  char* ws = (char*)d_ws;
  unsigned short* gbf = (unsigned short*)ws;                 // 16,777,216 B
  float* rscale = (float*)(ws + 16777216);                   // 262,144
  float* ssum   = (float*)(ws + 17039360);                   // 262,144
  float* d5     = (float*)(ws + 17301504);                   // 1,310,720
  unsigned short* W1T = (unsigned short*)(ws + 18612224);    // 32,768
  unsigned short* W2T = (unsigned short*)(ws + 18644992);    // 32,768
  unsigned short* fbf = (unsigned short*)(ws + 18677760);    // 16,777,216 (optional tier)
  const bool useF = (ws_size >= (size_t)35454976);

  if(useF) k_pre<true ><<<BB*TDIM, 512, 0, stream>>>(feat, w, gbf, fbf, rscale, ssum);
  else     k_pre<false><<<BB*TDIM, 512, 0, stream>>>(feat, w, gbf, nullptr, rscale, ssum);
  k_wt<<<256, 128, 0, stream>>>(W1, W2, W1T, W2T);
  k_d5<<<BB*TDIM, 256, 0, stream>>>(feat, w, rscale, ssum, d5);
  if(useF) k_main<true ><<<BB*TTOUT, 512, 0, stream>>>(feat, gbf, fbf, d5, W1T, b1, W2T, b2, gamma, beta, out);
  else     k_main<false><<<BB*TTOUT, 512, 0, stream>>>(feat, gbf, nullptr, d5, W1T, b1, W2T, b2, gamma, beta, out);
}

// Round 4
// 116.611 us; speedup vs baseline: 1.0002x; 1.0002x over previous
//
#include <hip/hip_runtime.h>
#include <math.h>

#define BB    8
#define TDIM  64
#define NN    128
#define DD    128
#define TTOUT 62      // T-2
#define W3    384     // 3*N
#define LG    136     // ushort stride, 128-wide bf16 tiles (272B rows)
#define LPF   44      // ushort stride, sFt 32-wide tiles (88B rows, 8B-aligned odd cols)
#define LPP   44      // ushort stride, sP
#define LW    72      // ushort stride, FFN weight tiles (144B rows)

typedef __attribute__((ext_vector_type(8))) short bf16x8;
typedef __attribute__((ext_vector_type(4))) float f32x4;

__device__ __forceinline__ float sigf(float x){ return 1.0f/(1.0f+__expf(-x)); }
__device__ __forceinline__ unsigned short f2bf(float x){
  union{float f; unsigned u;} v; v.f=x;
  unsigned r = v.u + 0x7FFFu + ((v.u>>16)&1u);   // RNE
  return (unsigned short)(r>>16);
}

// K_pre: per t-block: rscale, gbf = bf16(rscale*sig*feat), fbf = bf16(feat), ssum = colsum(G) fp32
template<bool FBF>
__global__ __launch_bounds__(512) void k_pre(const float* __restrict__ feat,
    const float* __restrict__ w, unsigned short* __restrict__ gbf,
    unsigned short* __restrict__ fbf, float* __restrict__ rscale,
    float* __restrict__ ssum){
  __shared__ float sSig[DD];
  __shared__ float sPart[8*DD];
  const int bt = blockIdx.x, tid = threadIdx.x;
  if(tid < DD) sSig[tid] = sigf(w[tid]);
  __syncthreads();
  const int row = tid >> 2, q = tid & 3;
  const float* fp = feat + ((size_t)bt*NN + row)*DD + q*32;
  float f[32], g[32];
  #pragma unroll
  for(int i=0;i<8;i++){
    float4 v = *(const float4*)(fp + i*4);
    f[i*4]=v.x; f[i*4+1]=v.y; f[i*4+2]=v.z; f[i*4+3]=v.w;
  }
  float ss = 0.f;
  #pragma unroll
  for(int j=0;j<32;j++){ g[j] = f[j]*sSig[q*32+j]; ss += g[j]*g[j]; }
  ss += __shfl_xor(ss,1); ss += __shfl_xor(ss,2);
  float rs = 1.0f / fmaxf(sqrtf(ss), 1e-12f);
  if(q==0) rscale[(size_t)bt*NN + row] = rs;
  #pragma unroll
  for(int j=0;j<32;j++) g[j] *= rs;
  {
    unsigned u[16];
    #pragma unroll
    for(int j=0;j<16;j++) u[j] = (unsigned)f2bf(g[2*j]) | ((unsigned)f2bf(g[2*j+1])<<16);
    uint4* dst = (uint4*)(gbf + ((size_t)bt*NN+row)*DD + q*32);
    #pragma unroll
    for(int i=0;i<4;i++) dst[i] = *(uint4*)&u[i*4];
  }
  if(FBF){
    unsigned u[16];
    #pragma unroll
    for(int j=0;j<16;j++) u[j] = (unsigned)f2bf(f[2*j]) | ((unsigned)f2bf(f[2*j+1])<<16);
    uint4* dst = (uint4*)(fbf + ((size_t)bt*NN+row)*DD + q*32);
    #pragma unroll
    for(int i=0;i<4;i++) dst[i] = *(uint4*)&u[i*4];
  }
  // column sums of G over this block's 128 rows (fp32, pre-rounding)
  #pragma unroll
  for(int k=4;k<64;k<<=1){
    #pragma unroll
    for(int j=0;j<32;j++) g[j] += __shfl_xor(g[j], k);
  }
  const int lane = tid & 63, wid = tid >> 6;
  if((lane>>2)==0){
    #pragma unroll
    for(int j=0;j<32;j++) sPart[wid*DD + q*32 + j] = g[j];
  }
  __syncthreads();
  if(tid < DD){
    float s = 0.f;
    #pragma unroll
    for(int wv=0; wv<8; wv++) s += sPart[wv*DD + tid];
    ssum[(size_t)bt*DD + tid] = s;
  }
}

// K_wt: W1,W2 -> transposed bf16
__global__ void k_wt(const float* __restrict__ W1, const float* __restrict__ W2,
                     unsigned short* __restrict__ W1T, unsigned short* __restrict__ W2T){
  int k = blockIdx.x & 127, m = blockIdx.x >> 7;
  int n = threadIdx.x;
  const float* W = m ? W2 : W1;
  unsigned short* WT = m ? W2T : W1T;
  WT[n*DD + k] = f2bf(W[(size_t)k*DD + n]);
}

// K_d5: d5[r][k] = rscale_r * sum_d feat[r][d]*sig[d]*ssum[t(r)-2+k][d], k=0..4 (fp32, sign-accurate)
__global__ __launch_bounds__(256) void k_d5(const float* __restrict__ feat,
    const float* __restrict__ w, const float* __restrict__ rscale,
    const float* __restrict__ ssum, float* __restrict__ d5){
  __shared__ float s5[5*DD];
  const int tb = blockIdx.x, tid = threadIdx.x;
  for(int e=tid; e<5*DD; e+=256){
    int k = e>>7, d = e&127;
    int t2 = (tb & 63) - 2 + k;
    float v = 0.f;
    if(t2 >= 0 && t2 < TDIM) v = sigf(w[d]) * ssum[(size_t)(tb + k - 2)*DD + d];
    s5[k*DD + d] = v;
  }
  __syncthreads();
  const int row = tid>>1, h = tid&1;
  const float* fp = feat + ((size_t)tb*NN + row)*DD + h*64;
  float a0=0,a1=0,a2=0,a3=0,a4=0;
  #pragma unroll
  for(int i=0;i<16;i++){
    float4 v = *(const float4*)(fp + i*4);
    const float* s0 = s5 + h*64 + i*4;
    a0 += v.x*s0[0*DD+0] + v.y*s0[0*DD+1] + v.z*s0[0*DD+2] + v.w*s0[0*DD+3];
    a1 += v.x*s0[1*DD+0] + v.y*s0[1*DD+1] + v.z*s0[1*DD+2] + v.w*s0[1*DD+3];
    a2 += v.x*s0[2*DD+0] + v.y*s0[2*DD+1] + v.z*s0[2*DD+2] + v.w*s0[2*DD+3];
    a3 += v.x*s0[3*DD+0] + v.y*s0[3*DD+1] + v.z*s0[3*DD+2] + v.w*s0[3*DD+3];
    a4 += v.x*s0[4*DD+0] + v.y*s0[4*DD+1] + v.z*s0[4*DD+2] + v.w*s0[4*DD+3];
  }
  a0 += __shfl_xor(a0,1); a1 += __shfl_xor(a1,1); a2 += __shfl_xor(a2,1);
  a3 += __shfl_xor(a3,1); a4 += __shfl_xor(a4,1);
  if(h==0){
    float rs = rscale[(size_t)tb*NN + row];
    float* dp = d5 + ((size_t)tb*NN + row)*5;
    dp[0]=a0*rs; dp[1]=a1*rs; dp[2]=a2*rs; dp[3]=a3*rs; dp[4]=a4*rs;
  }
}

// K_main: per (b,tt): dis from d5; P = dis*(G·Gᵀ)*dis (MFMA); agg = P·F (MFMA); FFN (MFMA); res+LN
template<bool FBF>
__global__ __launch_bounds__(512,4) void k_main(
    const float* __restrict__ feat,
    const unsigned short* __restrict__ gbf,
    const unsigned short* __restrict__ fbf,
    const float* __restrict__ d5,
    const unsigned short* __restrict__ W1T, const float* __restrict__ b1,
    const unsigned short* __restrict__ W2T, const float* __restrict__ b2,
    const float* __restrict__ gamma, const float* __restrict__ beta,
    float* __restrict__ out)
{
  __shared__ __align__(16) unsigned short sm[33024];
  __shared__ float sDis[W3];
  unsigned short* sA  = sm;            // 128 x LG : G rows 256..383 (A of gram; later agg, h)
  unsigned short* sG  = sm + 17408;    // 32 x LG  : G chunk rows
  unsigned short* sFt = sm + 21760;    // 128 x LPF: F chunk transposed [d][n]
  unsigned short* sP  = sm + 27392;    // 128 x LPP: P chunk bf16
  unsigned short* sWt = sm + 17408;    // 128 x LW : FFN weight tiles (overlay)

  const int bt2 = blockIdx.x;
  const int tid = threadIdx.x;
  const int rowBase = (bt2/TTOUT)*TDIM*NN + (bt2%TTOUT)*NN;

  const int lane = tid & 63, wid = tid >> 6;
  const int l15 = lane & 15, l4 = lane >> 4;
  const int m0 = wid * 16;

  // dis for all 384 window rows
  if(tid < W3){
    int jb = tid >> 7;
    const float* dp = d5 + (size_t)(rowBase + tid)*5 + (2 - jb);
    float deg = dp[0] + dp[1] + dp[2];
    sDis[tid] = (deg > 0.f) ? rsqrtf(fmaxf(deg, 1e-38f)) : 0.f;
  }

  // sA copy: 128 rows x 16 segs
  #pragma unroll
  for(int it=0; it<4; ++it){
    int e = it*512 + tid;
    int r = e >> 4, sg = e & 15;
    uint4 v = *(const uint4*)(gbf + (size_t)(rowBase+256+r)*DD + sg*8);
    *(uint4*)(sA + r*LG + sg*8) = v;
  }

  f32x4 acc2[8];
  #pragma unroll
  for(int i=0;i<8;i++) acc2[i] = (f32x4){0.f,0.f,0.f,0.f};

  for(int c=0; c<12; ++c){
    const int n0 = c*32;
    __syncthreads();   // prev phase2 done with sG/sFt/sP (c=0: sA/sDis ready)
    // sG: 32 rows x 16 segs = 512
    {
      int r = tid >> 4, sg = tid & 15;
      uint4 v = *(const uint4*)(gbf + (size_t)(rowBase+n0+r)*DD + sg*8);
      *(uint4*)(sG + r*LG + sg*8) = v;
    }
    // sFt: transpose-stage F chunk; thread = (col-pair, row-group of 4)
    {
      int p = tid & 63, rg = tid >> 6;
      int d0 = p*2, r0 = rg*4;
      unsigned v0,v1,v2,v3;
      if(FBF){
        v0 = *(const unsigned*)(fbf + (size_t)(rowBase+n0+r0+0)*DD + d0);
        v1 = *(const unsigned*)(fbf + (size_t)(rowBase+n0+r0+1)*DD + d0);
        v2 = *(const unsigned*)(fbf + (size_t)(rowBase+n0+r0+2)*DD + d0);
        v3 = *(const unsigned*)(fbf + (size_t)(rowBase+n0+r0+3)*DD + d0);
      } else {
        float2 a0 = *(const float2*)(feat + (size_t)(rowBase+n0+r0+0)*DD + d0);
        float2 a1 = *(const float2*)(feat + (size_t)(rowBase+n0+r0+1)*DD + d0);
        float2 a2 = *(const float2*)(feat + (size_t)(rowBase+n0+r0+2)*DD + d0);
        float2 a3 = *(const float2*)(feat + (size_t)(rowBase+n0+r0+3)*DD + d0);
        v0 = (unsigned)f2bf(a0.x) | ((unsigned)f2bf(a0.y)<<16);
        v1 = (unsigned)f2bf(a1.x) | ((unsigned)f2bf(a1.y)<<16);
        v2 = (unsigned)f2bf(a2.x) | ((unsigned)f2bf(a2.y)<<16);
        v3 = (unsigned)f2bf(a3.x) | ((unsigned)f2bf(a3.y)<<16);
      }
      uint2 lo, hi;
      lo.x = (v0 & 0xffffu) | (v1 << 16);
      lo.y = (v2 & 0xffffu) | (v3 << 16);
      hi.x = (v0 >> 16) | (v1 & 0xffff0000u);
      hi.y = (v2 >> 16) | (v3 & 0xffff0000u);
      *(uint2*)(sFt + (size_t)d0*LPF + r0)     = lo;
      *(uint2*)(sFt + (size_t)(d0+1)*LPF + r0) = hi;
    }
    __syncthreads();

    // phase1: P[:, n0:+32] = A(128xK128) x Gchunk^T, dis applied in epilogue
    f32x4 p0 = {0.f,0.f,0.f,0.f}, p1 = {0.f,0.f,0.f,0.f};
    #pragma unroll
    for(int ks=0; ks<4; ++ks){
      bf16x8 aA  = *(const bf16x8*)&sA[(m0+l15)*LG + ks*32 + l4*8];
      bf16x8 bg0 = *(const bf16x8*)&sG[( 0+l15)*LG + ks*32 + l4*8];
      bf16x8 bg1 = *(const bf16x8*)&sG[(16+l15)*LG + ks*32 + l4*8];
      p0 = __builtin_amdgcn_mfma_f32_16x16x32_bf16(aA, bg0, p0, 0,0,0);
      p1 = __builtin_amdgcn_mfma_f32_16x16x32_bf16(aA, bg1, p1, 0,0,0);
    }
    {
      float dn0 = sDis[n0 + l15], dn1 = sDis[n0 + 16 + l15];
      #pragma unroll
      for(int r=0;r<4;r++){
        float dm = sDis[256 + m0 + l4*4 + r];
        sP[(m0+l4*4+r)*LPP +  0 + l15] = f2bf(p0[r]*dm*dn0);
        sP[(m0+l4*4+r)*LPP + 16 + l15] = f2bf(p1[r]*dm*dn1);
      }
    }
    __syncthreads();

    // phase2: agg += P(128x32) x F(32x128)
    bf16x8 aP = *(const bf16x8*)&sP[(m0+l15)*LPP + l4*8];
    #pragma unroll
    for(int dt=0; dt<8; ++dt){
      bf16x8 bF = *(const bf16x8*)&sFt[(dt*16+l15)*LPF + l4*8];
      acc2[dt] = __builtin_amdgcn_mfma_f32_16x16x32_bf16(aP, bF, acc2[dt], 0,0,0);
    }
  }

  // agg -> sA (bf16); wave-strip-local, no sync needed
  #pragma unroll
  for(int dt=0; dt<8; ++dt)
    #pragma unroll
    for(int r=0;r<4;r++)
      sA[(m0+l4*4+r)*LG + dt*16+l15] = f2bf(acc2[dt][r]);

  // GEMM1: h = relu(agg @ W1 + b1)
  f32x4 acch[8];
  #pragma unroll
  for(int dt=0; dt<8; ++dt){
    float bv = b1[dt*16+l15];
    acch[dt] = (f32x4){bv,bv,bv,bv};
  }
  for(int kh=0; kh<2; ++kh){
    __syncthreads();   // all phase2/前 sWt reads done
    #pragma unroll
    for(int it=0; it<2; ++it){
      int e = it*512 + tid;       // 1024: 128 rows x 8 segs
      int n = e>>3, sg = e&7;
      uint4 v = *(const uint4*)(W1T + (size_t)n*DD + kh*64 + sg*8);
      *(uint4*)(sWt + n*LW + sg*8) = v;
    }
    __syncthreads();
    #pragma unroll
    for(int ks=0; ks<2; ++ks){
      bf16x8 aA = *(const bf16x8*)&sA[(m0+l15)*LG + kh*64 + ks*32 + l4*8];
      #pragma unroll
      for(int dt=0; dt<8; ++dt){
        bf16x8 bW = *(const bf16x8*)&sWt[(dt*16+l15)*LW + ks*32 + l4*8];
        acch[dt] = __builtin_amdgcn_mfma_f32_16x16x32_bf16(aA, bW, acch[dt], 0,0,0);
      }
    }
  }
  __syncthreads();   // GEMM1 done before h overwrites sA (A-reads were strip-local, but keep safe)
  #pragma unroll
  for(int dt=0; dt<8; ++dt)
    #pragma unroll
    for(int r=0;r<4;r++)
      sA[(m0+l4*4+r)*LG + dt*16+l15] = f2bf(fmaxf(acch[dt][r], 0.f));

  // GEMM2: o = h @ W2 + b2
  f32x4 acco[8];
  #pragma unroll
  for(int dt=0; dt<8; ++dt){
    float bv = b2[dt*16+l15];
    acco[dt] = (f32x4){bv,bv,bv,bv};
  }
  for(int kh=0; kh<2; ++kh){
    __syncthreads();
    #pragma unroll
    for(int it=0; it<2; ++it){
      int e = it*512 + tid;
      int n = e>>3, sg = e&7;
      uint4 v = *(const uint4*)(W2T + (size_t)n*DD + kh*64 + sg*8);
      *(uint4*)(sWt + n*LW + sg*8) = v;
    }
    __syncthreads();
    #pragma unroll
    for(int ks=0; ks<2; ++ks){
      bf16x8 aA = *(const bf16x8*)&sA[(m0+l15)*LG + kh*64 + ks*32 + l4*8];
      #pragma unroll
      for(int dt=0; dt<8; ++dt){
        bf16x8 bW = *(const bf16x8*)&sWt[(dt*16+l15)*LW + ks*32 + l4*8];
        acco[dt] = __builtin_amdgcn_mfma_f32_16x16x32_bf16(aA, bW, acco[dt], 0,0,0);
      }
    }
  }

  // residual + LayerNorm (fp32)
  const float* fres = feat + (size_t)(rowBase + 256)*DD;
  #pragma unroll
  for(int r=0;r<4;r++){
    int m = m0 + l4*4 + r;
    float vals[8]; float s1 = 0.f, s2 = 0.f;
    #pragma unroll
    for(int dt=0; dt<8; ++dt){
      int d = dt*16 + l15;
      float v = acco[dt][r] + fres[(size_t)m*DD + d];
      vals[dt] = v; s1 += v; s2 += v*v;
    }
    #pragma unroll
    for(int k=1;k<16;k<<=1){ s1 += __shfl_xor(s1,k); s2 += __shfl_xor(s2,k); }
    float mu   = s1*(1.0f/DD);
    float rstd = rsqrtf(s2*(1.0f/DD) - mu*mu + 1e-5f);
    #pragma unroll
    for(int dt=0; dt<8; ++dt){
      int d = dt*16 + l15;
      out[((size_t)bt2*NN + m)*DD + d] = (vals[dt]-mu)*rstd*gamma[d] + beta[d];
    }
  }
}

extern "C" void kernel_launch(void* const* d_in, const int* in_sizes, int n_in,
                              void* d_out, int out_size, void* d_ws, size_t ws_size,
                              hipStream_t stream){
  const float* feat  = (const float*)d_in[0];
  const float* w     = (const float*)d_in[1];
  const float* W1    = (const float*)d_in[2];
  const float* b1    = (const float*)d_in[3];
  const float* W2    = (const float*)d_in[4];
  const float* b2    = (const float*)d_in[5];
  const float* gamma = (const float*)d_in[6];
  const float* beta  = (const float*)d_in[7];
  float* out = (float*)d_out;

  char* ws = (char*)d_ws;
  unsigned short* gbf = (unsigned short*)ws;                 // 16,777,216 B
  float* rscale = (float*)(ws + 16777216);                   // 262,144
  float* ssum   = (float*)(ws + 17039360);                   // 262,144
  float* d5     = (float*)(ws + 17301504);                   // 1,310,720
  unsigned short* W1T = (unsigned short*)(ws + 18612224);    // 32,768
  unsigned short* W2T = (unsigned short*)(ws + 18644992);    // 32,768
  unsigned short* fbf = (unsigned short*)(ws + 18677760);    // 16,777,216 (optional tier)
  const bool useF = (ws_size >= (size_t)35454976);

  if(useF) k_pre<true ><<<BB*TDIM, 512, 0, stream>>>(feat, w, gbf, fbf, rscale, ssum);
  else     k_pre<false><<<BB*TDIM, 512, 0, stream>>>(feat, w, gbf, nullptr, rscale, ssum);
  k_wt<<<256, 128, 0, stream>>>(W1, W2, W1T, W2T);
  k_d5<<<BB*TDIM, 256, 0, stream>>>(feat, w, rscale, ssum, d5);
  if(useF) k_main<true ><<<BB*TTOUT, 512, 0, stream>>>(feat, gbf, fbf, d5, W1T, b1, W2T, b2, gamma, beta, out);
  else     k_main<false><<<BB*TTOUT, 512, 0, stream>>>(feat, gbf, nullptr, d5, W1T, b1, W2T, b2, gamma, beta, out);
}